// Round 8
// baseline (464.621 us; speedup 1.0000x reference)
//
#include <hip/hip_runtime.h>
#include <hip/hip_cooperative_groups.h>
#include <math.h>

namespace cg = cooperative_groups;

#define N_ 32
#define T_ 2048
#define E_ 512
#define D_ 1024
#define U_ 256

typedef __attribute__((ext_vector_type(8))) short bf16x8;
typedef __attribute__((ext_vector_type(16))) float f32x16;

__device__ __forceinline__ short f2bf_rne(float x) {
  unsigned int u = __float_as_uint(x);
  unsigned int r = u + 0x7FFFu + ((u >> 16) & 1u);
  return (short)(r >> 16);
}
__device__ __forceinline__ short f2bf_trunc(float x) {
  return (short)(__float_as_uint(x) >> 16);
}
__device__ __forceinline__ float bf2f(short h) {
  return __uint_as_float(((unsigned int)(unsigned short)h) << 16);
}
// tanh via hw exp2+rcp: tanh(x) = 1 - 2/(e^{2x}+1); saturates correctly at +-inf
__device__ __forceinline__ float fast_tanh(float x) {
  float t = exp2f(x * 2.8853900817779268f);   // e^{2x}, v_exp_f32
  return 1.0f - 2.0f * __builtin_amdgcn_rcpf(t + 1.0f);
}
__device__ __forceinline__ float fast_sigmoid(float w) {
  return __builtin_amdgcn_rcpf(1.0f + exp2f(-1.4426950408889634f * w));
}

// 256-entry inclusive scan over one 256-thread virtual WG; __syncthreads spans
// the whole 512-thread block, so BOTH halves must call it in lockstep (they do:
// phase C is uniform across the two halves of the blocks that run it).
__device__ __forceinline__ float block_incl_scan(float val, float* sbuf, int vtid) {
  float x = val;
  sbuf[vtid] = x;
  __syncthreads();
#pragma unroll
  for (int off = 1; off < 256; off <<= 1) {
    float t = (vtid >= off) ? sbuf[vtid - off] : 0.f;
    __syncthreads();
    x += t;
    sbuf[vtid] = x;
    __syncthreads();
  }
  return x;
}

// ================= single cooperative kernel: prep -> score -> scan -> ctx ===
// 256 blocks x 512 threads; each block = TWO independent 256-thread virtual
// WGs (vwg = blockIdx.x*2 + (tid>>8)) running the bit-identical r2 phase
// bodies on disjoint LDS (2x32KB score bufs + 2x2KB epilogue = 68KB). 68KB
// LDS caps occupancy at 1 block/CU, so 256 co-resident blocks trivially pass
// the cooperative-launch residency check that rejected r7's 512-block config
// (kernel never ran: outputs were all-zero). Per-CU shape equals r2's two
// 128-tile pipelines at 2 waves/SIMD (launch_bounds(512,2) -> <=256 regs).
__global__ __launch_bounds__(512, 2) void fused_kernel(
    const float* __restrict__ queries, const float* __restrict__ prev,
    const float* __restrict__ memory, const float* __restrict__ Wq,
    const float* __restrict__ Wk, const float* __restrict__ v,
    float* __restrict__ ctx_out, float* __restrict__ align_out,
    bf16x8* __restrict__ whiP, bf16x8* __restrict__ wloP,
    float* __restrict__ p_choose, float* __restrict__ pq_part) {
  __shared__ short sA[2][2][128 * 64];   // [sub][buf] : 64 KB
  __shared__ float smem_w[2][4][128];    // [sub]      : 4 KB

  cg::grid_group grid = cg::this_grid();
  const int tid = threadIdx.x;
  const int sub = tid >> 8;              // which virtual WG in this block
  const int vtid = tid & 255;
  const int vwg = blockIdx.x * 2 + sub;  // virtual WG id, 0..511

  // ---------------- phase A: Wk -> bf16 hi/lo B-frags (vwg 0..63)
  //                  + proj_q partials (vwg 64..191) ----------------
  if (vwg < 64) {
    const int fid = vwg * 256 + vtid;
    const int lane = fid & 63;
    const int ub = (fid >> 6) & 7;
    const int kc = (fid >> 9) & 3;
    const int c = fid >> 11;
    const int u = ub * 32 + (lane & 31);
    const int e0 = c * 64 + kc * 16 + (lane >> 5) * 8;
    bf16x8 H, L;
#pragma unroll
    for (int j = 0; j < 8; ++j) {
      float x = Wk[(size_t)(e0 + j) * U_ + u];   // lanes&31 consecutive over u
      short h = f2bf_trunc(x);
      H[j] = h;
      L[j] = f2bf_rne(x - bf2f(h));
    }
    whiP[fid] = H;
    wloP[fid] = L;
  } else if (vwg < 192) {
    const int ch = (vwg - 64) & 3;
    const int bb = (vwg - 64) >> 2;
    const int d0 = ch * 256;
    const float* q = queries + bb * D_ + d0;
    const float* wqp = Wq + (size_t)d0 * U_ + vtid;
    float acc = 0.f;
#pragma unroll 8
    for (int d = 0; d < 256; ++d)
      acc = fmaf(q[d], wqp[(size_t)d * U_], acc);   // q[d] wave-uniform
    pq_part[(bb * 4 + ch) * U_ + vtid] = acc;
  }

  __threadfence();
  grid.sync();

  // ---------------- phase B: score (exact r2 structure, 79.4us) ----------------
  {
    const int b = vwg >> 4;
    const int t0 = (vwg & 15) * 128;
    const int lane = vtid & 63;
    const int ty = vtid >> 6;
    const int l31 = lane & 31;
    const int half = lane >> 5;

    f32x16 acc[4][2];
#pragma unroll
    for (int mt = 0; mt < 4; ++mt)
#pragma unroll
      for (int nt = 0; nt < 2; ++nt)
#pragma unroll
        for (int r = 0; r < 16; ++r) acc[mt][nt][r] = 0.f;

    // staging: thread -> row sr = vtid>>1, col-half cs = (vtid&1)*16 of the 32-col step
    const int sr = vtid >> 1;
    const int cs = (vtid & 1) * 16;
    const int s0 = cs >> 3;                    // logical hi slot base: 0 or 2
    const int sw = sr & 7;
    const float* srow = memory + ((size_t)(b * T_ + t0 + sr)) * E_ + cs;
    char* const bp0 = (char*)&sA[sub][0][0] + sr * 128;
    char* const bp1 = (char*)&sA[sub][1][0] + sr * 128;

    float4 xr[4];
#pragma unroll
    for (int j = 0; j < 4; ++j) xr[j] = *(const float4*)(srow + j * 4);

    auto do_stage = [&](char* bp) {
      float xs[16] = {xr[0].x, xr[0].y, xr[0].z, xr[0].w,
                      xr[1].x, xr[1].y, xr[1].z, xr[1].w,
                      xr[2].x, xr[2].y, xr[2].z, xr[2].w,
                      xr[3].x, xr[3].y, xr[3].z, xr[3].w};
      bf16x8 H0, H1, L0, L1;
#pragma unroll
      for (int i = 0; i < 8; ++i) {
        short h0 = f2bf_trunc(xs[i]);
        H0[i] = h0;
        L0[i] = f2bf_rne(xs[i] - bf2f(h0));
        short h1 = f2bf_trunc(xs[8 + i]);
        H1[i] = h1;
        L1[i] = f2bf_rne(xs[8 + i] - bf2f(h1));
      }
      *(bf16x8*)(bp + (((s0 + 0) ^ sw) * 16)) = H0;
      *(bf16x8*)(bp + (((s0 + 1) ^ sw) * 16)) = H1;
      *(bf16x8*)(bp + (((s0 + 4) ^ sw) * 16)) = L0;
      *(bf16x8*)(bp + (((s0 + 5) ^ sw) * 16)) = L1;
    };

    do_stage(bp0);
    __syncthreads();

    int cur = 0;
    for (int it = 0; it < 16; ++it) {
      // prefetch next tile's globals (consumed after compute, in do_stage)
      if (it < 15) {
        const float* src = srow + (it + 1) * 32;
#pragma unroll
        for (int j = 0; j < 4; ++j) xr[j] = *(const float4*)(src + j * 4);
      }
      const char* base = (const char*)&sA[sub][cur][0];
#pragma unroll
      for (int kc = 0; kc < 2; ++kc) {
        bf16x8 bh[2], bl[2];
#pragma unroll
        for (int nt = 0; nt < 2; ++nt) {
          const int fidx = ((it * 2 + kc) * 8 + (ty * 2 + nt)) * 64 + lane;
          bh[nt] = whiP[fidx];
          bl[nt] = wloP[fidx];
        }
        const int sl = kc * 2 + half;
        bf16x8 ah[4], al[4];
#pragma unroll
        for (int mt = 0; mt < 4; ++mt) {
          const int m = mt * 32 + l31;
          ah[mt] = *(const bf16x8*)(base + (size_t)m * 128 + ((sl ^ (m & 7)) * 16));
          al[mt] = *(const bf16x8*)(base + (size_t)m * 128 + (((sl + 4) ^ (m & 7)) * 16));
        }
#pragma unroll
        for (int mt = 0; mt < 4; ++mt)
#pragma unroll
          for (int nt = 0; nt < 2; ++nt) {
            acc[mt][nt] = __builtin_amdgcn_mfma_f32_32x32x16_bf16(ah[mt], bh[nt], acc[mt][nt], 0, 0, 0);
            acc[mt][nt] = __builtin_amdgcn_mfma_f32_32x32x16_bf16(ah[mt], bl[nt], acc[mt][nt], 0, 0, 0);
            acc[mt][nt] = __builtin_amdgcn_mfma_f32_32x32x16_bf16(al[mt], bh[nt], acc[mt][nt], 0, 0, 0);
          }
      }
      // write next tile into the other buffer; its readers (iter it-1) are past
      // the barrier at end of it-1, and compute(it) only touched sA[sub][cur].
      if (it < 15) do_stage(cur ? bp0 : bp1);
      __syncthreads();
      cur ^= 1;
    }

    // epilogue: w[t] = sum_u tanh(score + pq[u]) * v[u]; p = sigmoid(w)
    const int u0 = ty * 64 + l31;
    const int u1 = u0 + 32;
    float pq0 = 0.f, pq1 = 0.f;
#pragma unroll
    for (int c = 0; c < 4; ++c) {
      pq0 += pq_part[(b * 4 + c) * U_ + u0];
      pq1 += pq_part[(b * 4 + c) * U_ + u1];
    }
    const float v0 = v[u0], v1 = v[u1];
#pragma unroll
    for (int mt = 0; mt < 4; ++mt)
#pragma unroll
      for (int r = 0; r < 16; ++r) {
        float s = fast_tanh(acc[mt][0][r] + pq0) * v0 + fast_tanh(acc[mt][1][r] + pq1) * v1;
#pragma unroll
        for (int off = 1; off < 32; off <<= 1) s += __shfl_xor(s, off, 64);
        if (l31 == 0) {
          const int row = mt * 32 + (r & 3) + 8 * (r >> 2) + 4 * half;
          smem_w[sub][ty][row] = s;
        }
      }
    __syncthreads();
    if (vtid < 128) {
      const float w = smem_w[sub][0][vtid] + smem_w[sub][1][vtid] +
                      smem_w[sub][2][vtid] + smem_w[sub][3][vtid];
      p_choose[b * T_ + t0 + vtid] = fast_sigmoid(w);
    }
  }

  __threadfence();
  grid.sync();

  // ---------------- phase C: monotonic scan (vwg 0..31) + zero ctx_out ---------
  // blocks 0..15 run it with BOTH halves active (uniform barrier counts).
  if (vwg < 32) {
    float* sbuf = &smem_w[sub][0][0];   // 256 floats per half
    const int b = vwg;
    ctx_out[b * E_ + vtid] = 0.f;
    ctx_out[b * E_ + 256 + vtid] = 0.f;
    const int base = b * T_ + vtid * 8;
    float4 p0 = *(const float4*)(p_choose + base);
    float4 p1 = *(const float4*)(p_choose + base + 4);
    float p[8] = {p0.x, p0.y, p0.z, p0.w, p1.x, p1.y, p1.z, p1.w};
    float s[8];
    float run = 0.f;
#pragma unroll
    for (int k = 0; k < 8; ++k) {
      float x = 1.0f - p[k];
      x = fminf(fmaxf(x, 1e-20f), 1.0f);
      run += logf(x);
      s[k] = run;
    }
    float incl = block_incl_scan(run, sbuf, vtid);
    float excl = incl - run;
    float cp[8];
#pragma unroll
    for (int k = 0; k < 8; ++k)
      cp[k] = expf(excl + (k ? s[k - 1] : 0.f));
    float4 r0 = *(const float4*)(prev + base);
    float4 r1 = *(const float4*)(prev + base + 4);
    float pr[8] = {r0.x, r0.y, r0.z, r0.w, r1.x, r1.y, r1.z, r1.w};
    float s2[8];
    float run2 = 0.f;
#pragma unroll
    for (int k = 0; k < 8; ++k) {
      float d = fminf(fmaxf(cp[k], 1e-10f), 1.0f);
      run2 += pr[k] / d;
      s2[k] = run2;
    }
    float incl2 = block_incl_scan(run2, sbuf, vtid);
    float excl2 = incl2 - run2;
#pragma unroll
    for (int k = 0; k < 8; ++k)
      p[k] = p[k] * cp[k] * (excl2 + s2[k]);
    *(float4*)(align_out + base) = make_float4(p[0], p[1], p[2], p[3]);
    *(float4*)(align_out + base + 4) = make_float4(p[4], p[5], p[6], p[7]);
  }

  __threadfence();
  grid.sync();

  // ---------------- phase D: contexts = alignments . memory (atomic accumulate)
  {
    const int b = vwg >> 4;
    const int t0 = (vwg & 15) * 128 + (vtid >> 7) * 64;
    const int col = (vtid & 127) * 4;
    const float* mrow = memory + ((size_t)(b * T_ + t0)) * E_ + col;
    const float* arow = align_out + b * T_ + t0;
    float4 a = make_float4(0.f, 0.f, 0.f, 0.f);
    for (int t = 0; t < 64; t += 4) {
      float4 m0 = *(const float4*)(mrow + (size_t)(t + 0) * E_);
      float4 m1 = *(const float4*)(mrow + (size_t)(t + 1) * E_);
      float4 m2 = *(const float4*)(mrow + (size_t)(t + 2) * E_);
      float4 m3 = *(const float4*)(mrow + (size_t)(t + 3) * E_);
      float a0 = arow[t], a1 = arow[t + 1], a2 = arow[t + 2], a3 = arow[t + 3];
      a.x = fmaf(a0, m0.x, a.x); a.y = fmaf(a0, m0.y, a.y);
      a.z = fmaf(a0, m0.z, a.z); a.w = fmaf(a0, m0.w, a.w);
      a.x = fmaf(a1, m1.x, a.x); a.y = fmaf(a1, m1.y, a.y);
      a.z = fmaf(a1, m1.z, a.z); a.w = fmaf(a1, m1.w, a.w);
      a.x = fmaf(a2, m2.x, a.x); a.y = fmaf(a2, m2.y, a.y);
      a.z = fmaf(a2, m2.z, a.z); a.w = fmaf(a2, m2.w, a.w);
      a.x = fmaf(a3, m3.x, a.x); a.y = fmaf(a3, m3.y, a.y);
      a.z = fmaf(a3, m3.z, a.z); a.w = fmaf(a3, m3.w, a.w);
    }
    float* dst = ctx_out + b * E_ + col;
    atomicAdd(dst + 0, a.x);
    atomicAdd(dst + 1, a.y);
    atomicAdd(dst + 2, a.z);
    atomicAdd(dst + 3, a.w);
  }
}

// ---------------- launch ----------------
extern "C" void kernel_launch(void* const* d_in, const int* in_sizes, int n_in,
                              void* d_out, int out_size, void* d_ws, size_t ws_size,
                              hipStream_t stream) {
  (void)in_sizes; (void)n_in; (void)out_size; (void)ws_size;
  const float* queries = (const float*)d_in[0];
  const float* prev    = (const float*)d_in[1];
  const float* memory  = (const float*)d_in[2];
  const float* Wq      = (const float*)d_in[3];
  const float* Wk      = (const float*)d_in[4];
  const float* v       = (const float*)d_in[5];

  float* out = (float*)d_out;
  float* ctx_out = out;              // [N,E]
  float* align_out = out + N_ * E_;  // [N,T]

  // ws layout (float slots): whiP [0,65536)  wloP [65536,131072)
  //   p_choose [131072,196608)  pq_part [196608,200704)
  float* ws = (float*)d_ws;
  bf16x8* whiP    = (bf16x8*)ws;
  bf16x8* wloP    = (bf16x8*)(ws + 65536);
  float* p_choose = ws + 131072;
  float* pq_part  = ws + 196608;

  void* args[] = {(void*)&queries, (void*)&prev, (void*)&memory, (void*)&Wq,
                  (void*)&Wk, (void*)&v, (void*)&ctx_out, (void*)&align_out,
                  (void*)&whiP, (void*)&wloP, (void*)&p_choose, (void*)&pq_part};
  hipLaunchCooperativeKernel((const void*)fused_kernel, dim3(256), dim3(512),
                             args, 0, stream);
}

// Round 9
// 272.547 us; speedup vs baseline: 1.7047x; 1.7047x over previous
//
#include <hip/hip_runtime.h>
#include <math.h>

#define N_ 32
#define T_ 2048
#define E_ 512
#define D_ 1024
#define U_ 256

typedef __attribute__((ext_vector_type(8))) short bf16x8;
typedef __attribute__((ext_vector_type(16))) float f32x16;

__device__ __forceinline__ short f2bf_rne(float x) {
  unsigned int u = __float_as_uint(x);
  unsigned int r = u + 0x7FFFu + ((u >> 16) & 1u);
  return (short)(r >> 16);
}
__device__ __forceinline__ short f2bf_trunc(float x) {
  return (short)(__float_as_uint(x) >> 16);
}
__device__ __forceinline__ float bf2f(short h) {
  return __uint_as_float(((unsigned int)(unsigned short)h) << 16);
}
// tanh via hw exp2+rcp: tanh(x) = 1 - 2/(e^{2x}+1); saturates correctly at +-inf
__device__ __forceinline__ float fast_tanh(float x) {
  float t = exp2f(x * 2.8853900817779268f);   // e^{2x}, v_exp_f32
  return 1.0f - 2.0f * __builtin_amdgcn_rcpf(t + 1.0f);
}
__device__ __forceinline__ float fast_sigmoid(float w) {
  return __builtin_amdgcn_rcpf(1.0f + exp2f(-1.4426950408889634f * w));
}

// direct global->LDS DMA, 16B per lane. dst must be the wave-uniform lane-0
// base (HW adds lane*16); src is per-lane.
__device__ __forceinline__ void gload_lds16(const float* src, void* dst) {
  __builtin_amdgcn_global_load_lds(
      (const __attribute__((address_space(1))) void*)src,
      (__attribute__((address_space(3))) void*)dst, 16, 0, 0);
}

// ---------------- K1: Wk -> bf16 hi/lo B-fragments (WGs 0..63)
//                 + proj_q partials (WGs 64..191) ----------------
// frag f = (kk*8+ub)*64+lane : u = ub*32+(lane&31), e = kk*16+(lane>>5)*8+j, kk=0..31
__global__ __launch_bounds__(256) void prep_kernel(
    const float* __restrict__ Wk, const float* __restrict__ queries,
    const float* __restrict__ Wq, bf16x8* __restrict__ whiP,
    bf16x8* __restrict__ wloP, float* __restrict__ pq_part) {
  const int wg = blockIdx.x, tid = threadIdx.x;
  if (wg < 64) {
    const int fid = wg * 256 + tid;
    const int lane = fid & 63;
    const int ub = (fid >> 6) & 7;
    const int kc = (fid >> 9) & 3;
    const int c = fid >> 11;
    const int u = ub * 32 + (lane & 31);
    const int e0 = c * 64 + kc * 16 + (lane >> 5) * 8;
    bf16x8 H, L;
#pragma unroll
    for (int j = 0; j < 8; ++j) {
      float x = Wk[(size_t)(e0 + j) * U_ + u];   // lanes&31 consecutive over u
      short h = f2bf_trunc(x);
      H[j] = h;
      L[j] = f2bf_rne(x - bf2f(h));
    }
    whiP[fid] = H;
    wloP[fid] = L;
  } else {
    const int ch = (wg - 64) & 3;
    const int bb = (wg - 64) >> 2;
    const int d0 = ch * 256;
    const float* q = queries + bb * D_ + d0;
    const float* wq = Wq + (size_t)d0 * U_ + tid;
    float acc = 0.f;
#pragma unroll 8
    for (int d = 0; d < 256; ++d)
      acc = fmaf(q[d], wq[(size_t)d * U_], acc);   // q[d] wave-uniform
    pq_part[(bb * 4 + ch) * U_ + tid] = acc;
  }
}

// ---------------- K2: score via split-bf16 MFMA, global_load_lds staging -----
// Grid 512 (T/128 x N); WG 256 = 4 waves; WG tile 128t x 256u; wave 128t x 64u
// = 4x2 mfma_f32_32x32x16_bf16, 3-product hi/lo split (acc[4][2] = 128 AGPRs).
// vs r2 (79.4us): staging is now direct global->LDS DMA of RAW FP32
// (4 x global_load_lds_dwordx4 per wave per iter, zero staging VGPRs, no
// convert/ds_write tail before the barrier — the m97 pattern: STAGE(next) ->
// compute(cur) -> barrier). The fp32->bf16 hi/lo split moves to frag-read
// time in registers (identical per-element arithmetic + identical MFMA order
// -> absmax bit-identical; 4x redundant across waves but on the idle VALU
// pipe, overlapping MFMA). LDS layout: [2][128 rows][8 slots x 16B] fp32,
// physical slot = logical ^ (row&7); the gl_lds linear write is matched by
// pre-swizzling the per-lane GLOBAL source (both-sides rule): linear chunk
// C -> row C>>3, phys slot C&7, source cols = ((C&7)^(row&7))*4.
__global__ __launch_bounds__(256, 2) void score_kernel(
    const float* __restrict__ memory, const bf16x8* __restrict__ whiP,
    const bf16x8* __restrict__ wloP, const float* __restrict__ pq_part,
    const float* __restrict__ v, float* __restrict__ p_choose) {
  __shared__ float sAf[2][128 * 32];   // 2 x 16 KB fp32 tiles
  __shared__ float smem_w[4][128];     // 2 KB

  const int b = blockIdx.y;
  const int t0 = blockIdx.x * 128;
  const int tid = threadIdx.x;
  const int lane = tid & 63;
  const int ty = tid >> 6;
  const int l31 = lane & 31;
  const int half = lane >> 5;

  f32x16 acc[4][2];
#pragma unroll
  for (int mt = 0; mt < 4; ++mt)
#pragma unroll
    for (int nt = 0; nt < 2; ++nt)
#pragma unroll
      for (int r = 0; r < 16; ++r) acc[mt][nt][r] = 0.f;

  // staging source pointers: instruction i of this wave covers linear 16B
  // chunks C = (ty*4+i)*64 + lane of the 128x32-float tile.
  const float* gsrc[4];
  int ldsoff[4];   // wave-uniform byte offset of lane-0 dest within a buffer
#pragma unroll
  for (int i = 0; i < 4; ++i) {
    const int C = (ty * 4 + i) * 64 + lane;
    const int r = C >> 3;
    const int sl = (C & 7) ^ (r & 7);          // logical slot feeding phys C&7
    gsrc[i] = memory + ((size_t)(b * T_ + t0 + r)) * E_ + sl * 4;
    ldsoff[i] = (ty * 4 + i) * 1024;           // 64 lanes x 16B
  }

  auto do_stage = [&](int buf, int itn) {
    const int co = itn * 32;                   // tile column offset (floats)
#pragma unroll
    for (int i = 0; i < 4; ++i)
      gload_lds16(gsrc[i] + co, (char*)&sAf[buf][0] + ldsoff[i]);
  };

  // prologue: DMA tile 0 into buf 0; barrier drains vmcnt before first reads
  do_stage(0, 0);
  __syncthreads();

  for (int it = 0; it < 16; ++it) {
    // issue next tile's DMA first (lands during compute; drained by the
    // end-of-iter barrier's vmcnt(0); buf^1's readers finished last iter)
    if (it < 15) do_stage((it + 1) & 1, it + 1);

    const char* base = (const char*)&sAf[it & 1][0];
#pragma unroll
    for (int kc = 0; kc < 2; ++kc) {
      bf16x8 bh[2], bl[2];
#pragma unroll
      for (int nt = 0; nt < 2; ++nt) {
        const int fidx = ((it * 2 + kc) * 8 + (ty * 2 + nt)) * 64 + lane;
        bh[nt] = whiP[fidx];
        bl[nt] = wloP[fidx];
      }
      const int ls0 = half * 2 + kc * 4;       // logical 16B slot of k0
      bf16x8 ah[4], al[4];
#pragma unroll
      for (int mt = 0; mt < 4; ++mt) {
        const int m = mt * 32 + l31;
        const char* rowp = base + (size_t)m * 128;
        float4 f0 = *(const float4*)(rowp + ((ls0 ^ (m & 7)) * 16));
        float4 f1 = *(const float4*)(rowp + (((ls0 + 1) ^ (m & 7)) * 16));
        float xs[8] = {f0.x, f0.y, f0.z, f0.w, f1.x, f1.y, f1.z, f1.w};
#pragma unroll
        for (int i = 0; i < 8; ++i) {
          short h = f2bf_trunc(xs[i]);
          ah[mt][i] = h;
          al[mt][i] = f2bf_rne(xs[i] - bf2f(h));
        }
      }
#pragma unroll
      for (int mt = 0; mt < 4; ++mt)
#pragma unroll
        for (int nt = 0; nt < 2; ++nt) {
          acc[mt][nt] = __builtin_amdgcn_mfma_f32_32x32x16_bf16(ah[mt], bh[nt], acc[mt][nt], 0, 0, 0);
          acc[mt][nt] = __builtin_amdgcn_mfma_f32_32x32x16_bf16(ah[mt], bl[nt], acc[mt][nt], 0, 0, 0);
          acc[mt][nt] = __builtin_amdgcn_mfma_f32_32x32x16_bf16(al[mt], bh[nt], acc[mt][nt], 0, 0, 0);
        }
    }
    __syncthreads();
  }

  // epilogue: w[t] = sum_u tanh(score + pq[u]) * v[u]; p = sigmoid(w)
  const int u0 = ty * 64 + l31;
  const int u1 = u0 + 32;
  float pq0 = 0.f, pq1 = 0.f;
#pragma unroll
  for (int c = 0; c < 4; ++c) {
    pq0 += pq_part[(b * 4 + c) * U_ + u0];
    pq1 += pq_part[(b * 4 + c) * U_ + u1];
  }
  const float v0 = v[u0], v1 = v[u1];
#pragma unroll
  for (int mt = 0; mt < 4; ++mt)
#pragma unroll
    for (int r = 0; r < 16; ++r) {
      float s = fast_tanh(acc[mt][0][r] + pq0) * v0 + fast_tanh(acc[mt][1][r] + pq1) * v1;
#pragma unroll
      for (int off = 1; off < 32; off <<= 1) s += __shfl_xor(s, off, 64);
      if (l31 == 0) {
        const int row = mt * 32 + (r & 3) + 8 * (r >> 2) + 4 * half;
        smem_w[ty][row] = s;
      }
    }
  __syncthreads();
  if (tid < 128) {
    const float w = smem_w[0][tid] + smem_w[1][tid] + smem_w[2][tid] + smem_w[3][tid];
    p_choose[b * T_ + t0 + tid] = fast_sigmoid(w);
  }
}

// ---------------- K3: monotonic scan per batch row + zero ctx_out ----------------
__device__ __forceinline__ float block_incl_scan(float val, float* sbuf, int tid) {
  float x = val;
  sbuf[tid] = x;
  __syncthreads();
#pragma unroll
  for (int off = 1; off < 256; off <<= 1) {
    float t = (tid >= off) ? sbuf[tid - off] : 0.f;
    __syncthreads();
    x += t;
    sbuf[tid] = x;
    __syncthreads();
  }
  return x;
}

__global__ __launch_bounds__(256) void scan_kernel(
    const float* __restrict__ p_choose, const float* __restrict__ prev,
    float* __restrict__ align_out, float* __restrict__ ctx_out) {
  __shared__ float sbuf[256];
  const int b = blockIdx.x, tid = threadIdx.x;
  // zero this batch's ctx row (d_out is poisoned before every call)
  ctx_out[b * E_ + tid] = 0.f;
  ctx_out[b * E_ + 256 + tid] = 0.f;
  const int base = b * T_ + tid * 8;
  float4 p0 = *(const float4*)(p_choose + base);
  float4 p1 = *(const float4*)(p_choose + base + 4);
  float p[8] = {p0.x, p0.y, p0.z, p0.w, p1.x, p1.y, p1.z, p1.w};
  float s[8];
  float run = 0.f;
#pragma unroll
  for (int k = 0; k < 8; ++k) {
    float x = 1.0f - p[k];
    x = fminf(fmaxf(x, 1e-20f), 1.0f);
    run += logf(x);
    s[k] = run;
  }
  float incl = block_incl_scan(run, sbuf, tid);
  float excl = incl - run;
  float cp[8];
#pragma unroll
  for (int k = 0; k < 8; ++k)
    cp[k] = expf(excl + (k ? s[k - 1] : 0.f));
  float4 r0 = *(const float4*)(prev + base);
  float4 r1 = *(const float4*)(prev + base + 4);
  float pr[8] = {r0.x, r0.y, r0.z, r0.w, r1.x, r1.y, r1.z, r1.w};
  float s2[8];
  float run2 = 0.f;
#pragma unroll
  for (int k = 0; k < 8; ++k) {
    float d = fminf(fmaxf(cp[k], 1e-10f), 1.0f);
    run2 += pr[k] / d;
    s2[k] = run2;
  }
  float incl2 = block_incl_scan(run2, sbuf, tid);
  float excl2 = incl2 - run2;
#pragma unroll
  for (int k = 0; k < 8; ++k)
    p[k] = p[k] * cp[k] * (excl2 + s2[k]);
  *(float4*)(align_out + base) = make_float4(p[0], p[1], p[2], p[3]);
  *(float4*)(align_out + base + 4) = make_float4(p[4], p[5], p[6], p[7]);
}

// ---------------- K4: contexts = alignments . memory (atomic accumulate) ----------
// 512 WGs: wg -> (b, 128-row chunk); each half-WG does 64 rows x full E.
// Unroll-4 with batched loads: 4 float4 + 4 align scalars in flight per thread.
__global__ __launch_bounds__(256) void ctx_kernel(
    const float* __restrict__ memory, const float* __restrict__ align,
    float* __restrict__ ctx_out) {
  const int wg = blockIdx.x, tid = threadIdx.x;
  const int b = wg >> 4;
  const int t0 = (wg & 15) * 128 + (tid >> 7) * 64;
  const int col = (tid & 127) * 4;
  const float* mrow = memory + ((size_t)(b * T_ + t0)) * E_ + col;
  const float* arow = align + b * T_ + t0;
  float4 a = make_float4(0.f, 0.f, 0.f, 0.f);
  for (int t = 0; t < 64; t += 4) {
    float4 m0 = *(const float4*)(mrow + (size_t)(t + 0) * E_);
    float4 m1 = *(const float4*)(mrow + (size_t)(t + 1) * E_);
    float4 m2 = *(const float4*)(mrow + (size_t)(t + 2) * E_);
    float4 m3 = *(const float4*)(mrow + (size_t)(t + 3) * E_);
    float a0 = arow[t], a1 = arow[t + 1], a2 = arow[t + 2], a3 = arow[t + 3];
    a.x = fmaf(a0, m0.x, a.x); a.y = fmaf(a0, m0.y, a.y);
    a.z = fmaf(a0, m0.z, a.z); a.w = fmaf(a0, m0.w, a.w);
    a.x = fmaf(a1, m1.x, a.x); a.y = fmaf(a1, m1.y, a.y);
    a.z = fmaf(a1, m1.z, a.z); a.w = fmaf(a1, m1.w, a.w);
    a.x = fmaf(a2, m2.x, a.x); a.y = fmaf(a2, m2.y, a.y);
    a.z = fmaf(a2, m2.z, a.z); a.w = fmaf(a2, m2.w, a.w);
    a.x = fmaf(a3, m3.x, a.x); a.y = fmaf(a3, m3.y, a.y);
    a.z = fmaf(a3, m3.z, a.z); a.w = fmaf(a3, m3.w, a.w);
  }
  float* dst = ctx_out + b * E_ + col;
  atomicAdd(dst + 0, a.x);
  atomicAdd(dst + 1, a.y);
  atomicAdd(dst + 2, a.z);
  atomicAdd(dst + 3, a.w);
}

// ---------------- launch ----------------
extern "C" void kernel_launch(void* const* d_in, const int* in_sizes, int n_in,
                              void* d_out, int out_size, void* d_ws, size_t ws_size,
                              hipStream_t stream) {
  (void)in_sizes; (void)n_in; (void)out_size; (void)ws_size;
  const float* queries = (const float*)d_in[0];
  const float* prev    = (const float*)d_in[1];
  const float* memory  = (const float*)d_in[2];
  const float* Wq      = (const float*)d_in[3];
  const float* Wk      = (const float*)d_in[4];
  const float* v       = (const float*)d_in[5];

  float* out = (float*)d_out;
  float* ctx_out = out;              // [N,E]
  float* align_out = out + N_ * E_;  // [N,T]

  // ws layout (float slots): whiP [0,65536)  wloP [65536,131072)
  //   p_choose [131072,196608)  pq_part [196608,200704)
  float* ws = (float*)d_ws;
  bf16x8* whiP    = (bf16x8*)ws;
  bf16x8* wloP    = (bf16x8*)(ws + 65536);
  float* p_choose = ws + 131072;
  float* pq_part  = ws + 196608;

  prep_kernel<<<dim3(64 + 128), 256, 0, stream>>>(Wk, queries, Wq, whiP, wloP, pq_part);
  score_kernel<<<dim3(T_ / 128, N_), 256, 0, stream>>>(memory, whiP, wloP, pq_part, v, p_choose);
  scan_kernel<<<dim3(N_), 256, 0, stream>>>(p_choose, prev, align_out, ctx_out);
  ctx_kernel<<<dim3(512), 256, 0, stream>>>(memory, align_out, ctx_out);
}